// Round 14
// baseline (136.276 us; speedup 1.0000x reference)
//
#include <hip/hip_runtime.h>
#include <math.h>

#define N_FEAT_IN 256
#define N_HID 64
#define N_OUT 16
#define EPS 0.1f
#define NBINS 1024

typedef short bf16x8 __attribute__((ext_vector_type(8)));
typedef float f32x4 __attribute__((ext_vector_type(4)));

__device__ inline uint pack2(ushort a, ushort b) { return (uint)a | ((uint)b << 16); }

// fp32 -> bf16 round-to-nearest-even (inputs finite; no NaN handling needed)
__device__ inline ushort bf16_rne(float x) {
    uint b = __float_as_uint(x);
    b += 0x7fff + ((b >> 16) & 1);
    return (ushort)(b >> 16);
}

// unpack the two bf16 halves of a uint
__device__ inline float blo(uint u) { return __uint_as_float(u << 16); }
__device__ inline float bhi(uint u) { return __uint_as_float(u & 0xffff0000u); }

// truncation-based fp32 -> bf16 hi/lo split: x ~= hi + lo, |err| <= 2^-18 |x|
__device__ inline void split_bf16(float x, ushort& hi, ushort& lo) {
    uint b = __float_as_uint(x);
    hi = (ushort)(b >> 16);
    float xl = x - __uint_as_float(b & 0xffff0000u);
    lo = (ushort)(__float_as_uint(xl) >> 16);
}

// ---------------- zero (runtime fillBuffer is ~40us inside a graph) ----------------

__global__ void zero_int(int* __restrict__ p, int n) {
    int i = blockIdx.x * blockDim.x + threadIdx.x;
    if (i < n) p[i] = 0;
}

// ---------------- degree histogram, fused rank+row pack ----------------
// One atomic pass total: the atomic's return value IS the edge's rank among its
// target's edges. rr[e] = (rank<<16) | row[e] (both < 65536).

__global__ void hist_rank(const int* __restrict__ col, const int* __restrict__ row,
                          int* __restrict__ cnt, uint* __restrict__ rr, int E) {
    int e = blockIdx.x * blockDim.x + threadIdx.x;
    if (e < E) {
        int r = atomicAdd(&cnt[col[e]], 1);
        rr[e] = ((uint)r << 16) | (uint)row[e];
    }
}

// ---------------- 2-level exclusive scan, dinv + degree-histogram fused ----------------

__global__ void scan_chunks(const int* __restrict__ cnt, int* __restrict__ rowptr,
                            int* __restrict__ partial, float* __restrict__ dinv,
                            int* __restrict__ dhist, int N) {
    __shared__ int sm[256];
    __shared__ int h[NBINS];
    int tid = threadIdx.x;
    for (int b = tid; b < NBINS; b += 256) h[b] = 0;
    __syncthreads();
    int gid = blockIdx.x * 256 + tid;
    int v = (gid < N) ? cnt[gid] : 0;
    if (gid < N) atomicAdd(&h[min(v, NBINS - 1)], 1);   // LDS hist of degrees
    sm[tid] = v;
    __syncthreads();
#pragma unroll
    for (int off = 1; off < 256; off <<= 1) {
        int add = (tid >= off) ? sm[tid - off] : 0;
        __syncthreads();
        sm[tid] += add;
        __syncthreads();
    }
    if (gid < N) {
        rowptr[gid] = sm[tid] - v;               // exclusive within chunk
        dinv[gid] = rsqrtf(1.0f + (float)v);     // +1 for self loop
    }
    if (tid == 255) partial[blockIdx.x] = sm[255];
    __syncthreads();
    for (int b = tid; b < NBINS; b += 256)
        if (h[b]) atomicAdd(&dhist[b], h[b]);    // ~40 nonzero bins/block
}

// finish: every block redundantly scans the <=256 chunk partials in LDS (cheap)

__global__ void scan_finish(int* __restrict__ rowptr, const int* __restrict__ partial,
                            int N, int E, int nchunks) {
    __shared__ int sm[256];
    int tid = threadIdx.x;
    sm[tid] = (tid < nchunks) ? partial[tid] : 0;
    __syncthreads();
#pragma unroll
    for (int off = 1; off < 256; off <<= 1) {
        int add = (tid >= off) ? sm[tid - off] : 0;
        __syncthreads();
        sm[tid] += add;
        __syncthreads();
    }
    int boff = (blockIdx.x == 0) ? 0 : sm[blockIdx.x - 1];
    __syncthreads();
    int gid = blockIdx.x * 256 + tid;
    if (gid < N) rowptr[gid] += boff;
    if (gid == 0) rowptr[N] = E;
}

// ---------------- degree-bin exclusive scan (1 block, NBINS bins) ----------------

__global__ void deg_scan(int* __restrict__ dhist) {
    __shared__ int sums[256];
    int t = threadIdx.x;
    int v0 = dhist[4 * t], v1 = dhist[4 * t + 1];
    int v2 = dhist[4 * t + 2], v3 = dhist[4 * t + 3];
    int s = v0 + v1 + v2 + v3;
    sums[t] = s;
    __syncthreads();
#pragma unroll
    for (int off = 1; off < 256; off <<= 1) {
        int add = (t >= off) ? sums[t - off] : 0;
        __syncthreads();
        sums[t] += add;
        __syncthreads();
    }
    int excl = sums[t] - s;
    dhist[4 * t]     = excl;
    dhist[4 * t + 1] = excl + v0;
    dhist[4 * t + 2] = excl + v0 + v1;
    dhist[4 * t + 3] = excl + v0 + v1 + v2;
}

// ---------------- degree-sorted permutation (LDS-aggregated counting sort) ------------
// perm groups equal-degree nodes -> each layer wave gets 8 equal-degree nodes
// (kills the max-of-8 Poisson divergence, ~50% of gather-issue slots).

__global__ void perm_scatter(const int* __restrict__ cnt, int* __restrict__ dbase,
                             int* __restrict__ perm, int N) {
    __shared__ int h[NBINS];
    __shared__ int hb[NBINS];
    int tid = threadIdx.x;
    for (int b = tid; b < NBINS; b += 256) h[b] = 0;
    __syncthreads();
    int gid = blockIdx.x * 256 + tid;
    int d = 0, myrank = 0;
    bool valid = (gid < N);
    if (valid) {
        d = min(cnt[gid], NBINS - 1);
        myrank = atomicAdd(&h[d], 1);            // LDS atomic
    }
    __syncthreads();
    for (int b = tid; b < NBINS; b += 256) {
        int c = h[b];
        hb[b] = c ? atomicAdd(&dbase[b], c) : 0; // one global atomic per (block,bin)
    }
    __syncthreads();
    if (valid) perm[hb[d] + myrank] = gid;
}

// ---------------- atomic-free XCD-range-partitioned CSR scatter ----------------
// srcidx[rowptr[c] + rank] = src. Range partitioning (block&7 -> XCD round-robin)
// keeps each srcidx line in one XCD's L2. Kept SEPARATE from the gemm (round-10
// lesson: fusing this latency-bound role into the heavy gemm regressed 8x).

__global__ void csr_scatter_part(const int* __restrict__ col, const uint* __restrict__ rr,
                                 const int* __restrict__ rowptr,
                                 ushort* __restrict__ srcidx, int E, int rangeSz) {
    int r = blockIdx.x & 7;
    int nsl = gridDim.x >> 3;
    int s = blockIdx.x >> 3;
    int lo = r * rangeSz;
    int hi = lo + rangeSz;
    int stride = nsl * blockDim.x;
    for (int e = s * blockDim.x + threadIdx.x; e < E; e += stride) {
        int c = col[e];
        if (c >= lo && c < hi) {
            uint v = rr[e];
            srcidx[rowptr[c] + (v >> 16)] = (ushort)(v & 0xffffu);
        }
    }
}

// ---------------- As1 = dinv * relu(x @ W1 + b1), bf16-packed, via bf16x3 MFMA --------
// Each wave: 16 rows x 64 cols, register double-buffered x tiles.
// W1 hi/lo fragments staged once per block in LDS (64 KB -> 2 blocks/CU).
// A/B K-mapping k=(lane>>4)*8+i used identically for both operands (K-perm invariant).
// C/D: col=lane&15, row=(lane>>4)*4+reg.

__global__ __launch_bounds__(256) void gemm1_mfma(const float* __restrict__ x,
                                                  const float* __restrict__ W1,
                                                  const float* __restrict__ b1,
                                                  const float* __restrict__ dinv,
                                                  uint* __restrict__ AsOut,
                                                  int MB, int totalWaves) {
    __shared__ uint4 wh_lds[2048];  // 32 KB: [ks][nt][lane] hi fragments
    __shared__ uint4 wl_lds[2048];  // 32 KB: lo fragments
    int tid = threadIdx.x;
    for (int e = tid; e < 2048; e += 256) {
        int ks = e >> 8;
        int rem = e & 255;
        int nt = rem >> 6;
        int ln = rem & 63;
        int k0 = ks * 32 + ((ln >> 4) << 3);
        int colw = nt * 16 + (ln & 15);
        ushort hi[8], lo[8];
#pragma unroll
        for (int i = 0; i < 8; ++i) {
            float v = W1[(k0 + i) * 64 + colw];
            split_bf16(v, hi[i], lo[i]);
        }
        wh_lds[e] = make_uint4(pack2(hi[0], hi[1]), pack2(hi[2], hi[3]),
                               pack2(hi[4], hi[5]), pack2(hi[6], hi[7]));
        wl_lds[e] = make_uint4(pack2(lo[0], lo[1]), pack2(lo[2], lo[3]),
                               pack2(lo[4], lo[5]), pack2(lo[6], lo[7]));
    }
    __syncthreads();

    int lane = tid & 63;
    int m = lane & 15;
    int kg = lane >> 4;
    int wid = blockIdx.x * 4 + (tid >> 6);
    const bf16x8* whf = reinterpret_cast<const bf16x8*>(wh_lds);
    const bf16x8* wlf = reinterpret_cast<const bf16x8*>(wl_lds);
    float bias[4];
#pragma unroll
    for (int nt = 0; nt < 4; ++nt) bias[nt] = b1[nt * 16 + m];

    auto load_tile = [&](float4* dst, int mbv) {
        const float4* xr = reinterpret_cast<const float4*>(x) +
                           (size_t)(mbv * 16 + m) * 64 + kg * 2;
#pragma unroll
        for (int ks = 0; ks < 8; ++ks) {
            dst[2 * ks]     = xr[ks * 8];
            dst[2 * ks + 1] = xr[ks * 8 + 1];
        }
    };

    int mb = wid;
    if (mb >= MB) return;
    float4 xv[16], xn[16];
    load_tile(xv, mb);

    while (true) {
        int mbn = mb + totalWaves;
        bool has_next = (mbn < MB);
        if (has_next) load_tile(xn, mbn);   // issue loads early; hide under MFMA

        f32x4 acc[4] = {{0.f,0.f,0.f,0.f},{0.f,0.f,0.f,0.f},
                        {0.f,0.f,0.f,0.f},{0.f,0.f,0.f,0.f}};
#pragma unroll
        for (int ks = 0; ks < 8; ++ks) {
            float4 a0 = xv[2 * ks];
            float4 a1 = xv[2 * ks + 1];
            float f[8] = {a0.x, a0.y, a0.z, a0.w, a1.x, a1.y, a1.z, a1.w};
            bf16x8 ah, al;
#pragma unroll
            for (int i = 0; i < 8; ++i) {
                ushort hu, lu;
                split_bf16(f[i], hu, lu);
                ah[i] = (short)hu;
                al[i] = (short)lu;
            }
#pragma unroll
            for (int nt = 0; nt < 4; ++nt) {
                bf16x8 wh = whf[(ks * 4 + nt) * 64 + lane];
                bf16x8 wl = wlf[(ks * 4 + nt) * 64 + lane];
                acc[nt] = __builtin_amdgcn_mfma_f32_16x16x32_bf16(ah, wh, acc[nt], 0, 0, 0);
                acc[nt] = __builtin_amdgcn_mfma_f32_16x16x32_bf16(al, wh, acc[nt], 0, 0, 0);
                acc[nt] = __builtin_amdgcn_mfma_f32_16x16x32_bf16(ah, wl, acc[nt], 0, 0, 0);
            }
        }

        int r0 = mb * 16 + kg * 4;
        float dr[4];
#pragma unroll
        for (int j = 0; j < 4; ++j) dr[j] = dinv[r0 + j];
#pragma unroll
        for (int nt = 0; nt < 4; ++nt) {
#pragma unroll
            for (int j = 0; j < 4; ++j) {
                float v = fmaxf(acc[nt][j] + bias[nt], 0.0f) * dr[j];
                float p = __shfl_xor(v, 1, 64);  // partner column (m^1)
                if ((m & 1) == 0) {
                    uint u = pack2(bf16_rne(v), bf16_rne(p));
                    AsOut[(size_t)(r0 + j) * 32 + ((nt * 16 + m) >> 1)] = u;
                }
            }
        }

        if (!has_next) break;
#pragma unroll
        for (int u = 0; u < 16; ++u) xv[u] = xn[u];
        mb = mbn;
    }
}

// ---------------- fused FAGCN layer, 8 nodes per wave, degree-sorted ----------------
// 8 lanes per node, each lane owns 8 features (uint4 of bf16 pairs, 16 B/lane).
// Nodes walked via degree-sorted perm: all 8 nodes in a wave have equal degree.
// LAST variant fuses out = h @ W2 + b2 via LDS (2 output cols per lane).

template <bool LAST>
__global__ __launch_bounds__(256) void fagcn_layer(
    const uint4* __restrict__ As4, uint4* __restrict__ Out4,
    const float* __restrict__ dinv, const int* __restrict__ rowptr,
    const ushort* __restrict__ src, const int* __restrict__ perm,
    const float* __restrict__ att_l,
    const float* __restrict__ W2, const float* __restrict__ b2,
    float* __restrict__ out, int N) {
    __shared__ float W2s[64 * 16];   // 4 KB
    __shared__ float hL[32 * 68];    // 32 nodes x 64 (+4 pad)
    int tid = threadIdx.x;
    if (LAST) {
        for (int e = tid; e < 64 * 16; e += 256) W2s[e] = W2[e];
        __syncthreads();
    }
    int sub = tid & 7;               // feature octet index
    int lnode = tid >> 3;            // node within block (0..31)
    int gid = blockIdx.x * 32 + lnode;
    if (gid >= N) gid = N - 1;       // duplicate last slot (identical writes, benign)
    int i = perm[gid];

    int start = rowptr[i];
    int end = rowptr[i + 1];
    const uint4* Ab = As4 + sub;
    uint4 su = Ab[(size_t)i * 8];
    float s0 = blo(su.x), s1 = bhi(su.x), s2 = blo(su.y), s3 = bhi(su.y);
    float s4 = blo(su.z), s5 = bhi(su.z), s6 = blo(su.w), s7 = bhi(su.w);

    float aA0=0.f,aA1=0.f,aA2=0.f,aA3=0.f,aA4=0.f,aA5=0.f,aA6=0.f,aA7=0.f;
    float aB0=0.f,aB1=0.f,aB2=0.f,aB3=0.f,aB4=0.f,aB5=0.f,aB6=0.f,aB7=0.f;
    int j = start;
    for (; j + 3 < end; j += 4) {
        int e0 = src[j];
        int e1 = src[j + 1];
        int e2 = src[j + 2];
        int e3 = src[j + 3];
        uint4 u0 = Ab[(size_t)e0 * 8];
        uint4 u1 = Ab[(size_t)e1 * 8];
        uint4 u2 = Ab[(size_t)e2 * 8];
        uint4 u3 = Ab[(size_t)e3 * 8];
        aA0 += blo(u0.x); aA1 += bhi(u0.x); aA2 += blo(u0.y); aA3 += bhi(u0.y);
        aA4 += blo(u0.z); aA5 += bhi(u0.z); aA6 += blo(u0.w); aA7 += bhi(u0.w);
        aB0 += blo(u1.x); aB1 += bhi(u1.x); aB2 += blo(u1.y); aB3 += bhi(u1.y);
        aB4 += blo(u1.z); aB5 += bhi(u1.z); aB6 += blo(u1.w); aB7 += bhi(u1.w);
        aA0 += blo(u2.x); aA1 += bhi(u2.x); aA2 += blo(u2.y); aA3 += bhi(u2.y);
        aA4 += blo(u2.z); aA5 += bhi(u2.z); aA6 += blo(u2.w); aA7 += bhi(u2.w);
        aB0 += blo(u3.x); aB1 += bhi(u3.x); aB2 += blo(u3.y); aB3 += bhi(u3.y);
        aB4 += blo(u3.z); aB5 += bhi(u3.z); aB6 += blo(u3.w); aB7 += bhi(u3.w);
    }
    for (; j < end; ++j) {
        int s = src[j];
        uint4 u = Ab[(size_t)s * 8];
        aA0 += blo(u.x); aA1 += bhi(u.x); aA2 += blo(u.y); aA3 += bhi(u.y);
        aA4 += blo(u.z); aA5 += bhi(u.z); aA6 += blo(u.w); aA7 += bhi(u.w);
    }
    float c0 = aA0 + aB0, c1 = aA1 + aB1, c2 = aA2 + aB2, c3 = aA3 + aB3;
    float c4 = aA4 + aB4, c5 = aA5 + aB5, c6 = aA6 + aB6, c7 = aA7 + aB7;

    float d = dinv[i];
    // gate = sigmoid(dot(h_row, att)) with h = As/d
    float4 at0 = reinterpret_cast<const float4*>(att_l)[2 * sub];
    float4 at1 = reinterpret_cast<const float4*>(att_l)[2 * sub + 1];
    float prod = s0 * at0.x + s1 * at0.y + s2 * at0.z + s3 * at0.w +
                 s4 * at1.x + s5 * at1.y + s6 * at1.z + s7 * at1.w;
#pragma unroll
    for (int off = 4; off > 0; off >>= 1)
        prod += __shfl_xor(prod, off, 64);   // fold within 8-lane group
    float gate = 1.0f / (1.0f + expf(-prod / d));
    float factor = gate * (1.0f + EPS) - EPS;
    float df = d * factor;
    float h0 = df * (c0 + s0), h1 = df * (c1 + s1);
    float h2 = df * (c2 + s2), h3 = df * (c3 + s3);
    float h4 = df * (c4 + s4), h5 = df * (c5 + s5);
    float h6 = df * (c6 + s6), h7 = df * (c7 + s7);

    if (!LAST) {
        Out4[(size_t)i * 8 + sub] =
            make_uint4(pack2(bf16_rne(d * h0), bf16_rne(d * h1)),
                       pack2(bf16_rne(d * h2), bf16_rne(d * h3)),
                       pack2(bf16_rne(d * h4), bf16_rne(d * h5)),
                       pack2(bf16_rne(d * h6), bf16_rne(d * h7)));
    } else {
        // fused gemm2: h -> LDS, then each lane computes 2 output columns
        float4* hrow4 = reinterpret_cast<float4*>(&hL[lnode * 68]);
        hrow4[2 * sub]     = make_float4(h0, h1, h2, h3);
        hrow4[2 * sub + 1] = make_float4(h4, h5, h6, h7);
        __syncthreads();
        const float4* h4p = reinterpret_cast<const float4*>(&hL[lnode * 68]);
        float accA = b2[sub];
        float accB = b2[sub + 8];
#pragma unroll
        for (int k4 = 0; k4 < 16; ++k4) {
            float4 hv = h4p[k4];
            int k = 4 * k4;
            accA = fmaf(hv.x, W2s[(k + 0) * 16 + sub], accA);
            accB = fmaf(hv.x, W2s[(k + 0) * 16 + sub + 8], accB);
            accA = fmaf(hv.y, W2s[(k + 1) * 16 + sub], accA);
            accB = fmaf(hv.y, W2s[(k + 1) * 16 + sub + 8], accB);
            accA = fmaf(hv.z, W2s[(k + 2) * 16 + sub], accA);
            accB = fmaf(hv.z, W2s[(k + 2) * 16 + sub + 8], accB);
            accA = fmaf(hv.w, W2s[(k + 3) * 16 + sub], accA);
            accB = fmaf(hv.w, W2s[(k + 3) * 16 + sub + 8], accB);
        }
        out[(size_t)i * 16 + sub] = accA;
        out[(size_t)i * 16 + sub + 8] = accB;
    }
}

extern "C" void kernel_launch(void* const* d_in, const int* in_sizes, int n_in,
                              void* d_out, int out_size, void* d_ws, size_t ws_size,
                              hipStream_t stream) {
    const float* x   = (const float*)d_in[0];   // [N, 256]
    const int*   ei  = (const int*)d_in[1];     // [2, E] flat (int32 per harness)
    const float* W1  = (const float*)d_in[2];   // [256, 64]
    const float* b1  = (const float*)d_in[3];   // [64]
    const float* att = (const float*)d_in[4];   // [L, 1, 64]
    const float* W2  = (const float*)d_in[5];   // [64, 16]
    const float* b2  = (const float*)d_in[6];   // [16]
    float* out = (float*)d_out;                 // [N, 16]

    const int N = in_sizes[0] / N_FEAT_IN;      // 50000 (< 65536: ushort ids/ranks)
    const int E = in_sizes[1] / 2;              // 800000
    const int L = in_sizes[4] / N_HID;          // 2 layers

    const int* row = ei;       // edge_index[0] (source)
    const int* col = ei + E;   // edge_index[1] (target)

    // workspace layout (256B-aligned regions)
    char* wp = (char*)d_ws;
    auto alloc = [&](size_t bytes) -> char* {
        char* p = wp;
        wp += (bytes + 255) & ~(size_t)255;
        return p;
    };
    float*  dinv    = (float*)alloc((size_t)N * 4);
    int*    cnt     = (int*)alloc((size_t)(N + NBINS) * 4);  // cnt[N] + dhist[NBINS]
    int*    dhist   = cnt + N;
    int*    rowptr  = (int*)alloc((size_t)(N + 1) * 4);
    uint*   rr      = (uint*)alloc((size_t)E * 4);           // (rank<<16)|row per edge
    int*    partial = (int*)alloc(256 * 4);
    int*    perm    = (int*)alloc((size_t)N * 4);            // degree-sorted node order
    ushort* srcidx  = (ushort*)alloc((size_t)E * 2);
    uint*   AsA     = (uint*)alloc((size_t)N * 32 * 4);      // bf16-pair features
    uint*   AsB     = (uint*)alloc((size_t)N * 32 * 4);

    const int TB = 256;
    const int nchunks = (N + TB - 1) / TB;      // 196 <= 256
    const int rangeSz = (N + 7) / 8;            // XCD partition width
    const int PART_GRID = 1024;                 // 128 slices x 8 ranges

    // 1) degree+rank (one atomic pass) -> dinv, rowptr, degree-sorted perm, CSR
    zero_int<<<(N + NBINS + TB - 1) / TB, TB, 0, stream>>>(cnt, N + NBINS);
    hist_rank<<<(E + TB - 1) / TB, TB, 0, stream>>>(col, row, cnt, rr, E);
    scan_chunks<<<nchunks, TB, 0, stream>>>(cnt, rowptr, partial, dinv, dhist, N);
    scan_finish<<<nchunks, TB, 0, stream>>>(rowptr, partial, N, E, nchunks);
    deg_scan<<<1, TB, 0, stream>>>(dhist);
    perm_scatter<<<nchunks, TB, 0, stream>>>(cnt, dhist, perm, N);
    csr_scatter_part<<<PART_GRID, TB, 0, stream>>>(col, rr, rowptr, srcidx, E, rangeSz);

    // 2) As1 = dinv * relu(x @ W1 + b1) -> AsA (bf16 pairs)
    {
        const int blocks = 512;                 // 64 KB LDS -> 2 blocks/CU
        const int MB = N / 16;                  // 3125 row-tiles
        gemm1_mfma<<<blocks, TB, 0, stream>>>(x, W1, b1, dinv, AsA, MB, blocks * 4);
    }

    // 3) FAGCN layers over degree-sorted order; LAST fuses the final h @ W2 + b2
    {
        int grid = (N + 31) / 32;               // 32 nodes per 256-thread block
        uint4* A = (uint4*)AsA;
        uint4* B = (uint4*)AsB;
        for (int l = 0; l < L; ++l) {
            const float* att_l = att + (size_t)l * N_HID;
            if (l == L - 1) {
                fagcn_layer<true><<<grid, TB, 0, stream>>>(
                    A, B, dinv, rowptr, srcidx, perm, att_l, W2, b2, out, N);
            } else {
                fagcn_layer<false><<<grid, TB, 0, stream>>>(
                    A, B, dinv, rowptr, srcidx, perm, att_l, W2, b2, out, N);
                uint4* tmp = A; A = B; B = tmp;
            }
        }
    }
}

// Round 15
// 127.151 us; speedup vs baseline: 1.0718x; 1.0718x over previous
//
#include <hip/hip_runtime.h>
#include <math.h>

#define N_FEAT_IN 256
#define N_HID 64
#define N_OUT 16
#define EPS 0.1f

typedef short bf16x8 __attribute__((ext_vector_type(8)));
typedef float f32x4 __attribute__((ext_vector_type(4)));

__device__ inline uint pack2(ushort a, ushort b) { return (uint)a | ((uint)b << 16); }

// fp32 -> bf16 round-to-nearest-even (inputs finite; no NaN handling needed)
__device__ inline ushort bf16_rne(float x) {
    uint b = __float_as_uint(x);
    b += 0x7fff + ((b >> 16) & 1);
    return (ushort)(b >> 16);
}

// unpack the two bf16 halves of a uint
__device__ inline float blo(uint u) { return __uint_as_float(u << 16); }
__device__ inline float bhi(uint u) { return __uint_as_float(u & 0xffff0000u); }

// truncation-based fp32 -> bf16 hi/lo split: x ~= hi + lo, |err| <= 2^-18 |x|
__device__ inline void split_bf16(float x, ushort& hi, ushort& lo) {
    uint b = __float_as_uint(x);
    hi = (ushort)(b >> 16);
    float xl = x - __uint_as_float(b & 0xffff0000u);
    lo = (ushort)(__float_as_uint(xl) >> 16);
}

// ---------------- zero (runtime fillBuffer is ~40us inside a graph) ----------------

__global__ void zero_int(int* __restrict__ p, int n) {
    int i = blockIdx.x * blockDim.x + threadIdx.x;
    if (i < n) p[i] = 0;
}

// ---------------- degree histogram, fused rank+row pack ----------------
// One atomic pass total: the atomic's return value IS the edge's rank among its
// target's edges. rr[e] = (rank<<16) | row[e] (both < 65536: N=50000, max deg ~50)
// so the scatter pass reads ONE edge-payload array instead of rank+row separately.

__global__ void hist_rank(const int* __restrict__ col, const int* __restrict__ row,
                          int* __restrict__ cnt, uint* __restrict__ rr, int E) {
    int e = blockIdx.x * blockDim.x + threadIdx.x;
    if (e < E) {
        int r = atomicAdd(&cnt[col[e]], 1);
        rr[e] = ((uint)r << 16) | (uint)row[e];
    }
}

// ---------------- 2-level exclusive scan (N <= 256*256), dinv fused ----------------

__global__ void scan_chunks(const int* __restrict__ cnt, int* __restrict__ rowptr,
                            int* __restrict__ partial, float* __restrict__ dinv, int N) {
    __shared__ int sm[256];
    int tid = threadIdx.x;
    int gid = blockIdx.x * 256 + tid;
    int v = (gid < N) ? cnt[gid] : 0;
    sm[tid] = v;
    __syncthreads();
#pragma unroll
    for (int off = 1; off < 256; off <<= 1) {
        int add = (tid >= off) ? sm[tid - off] : 0;
        __syncthreads();
        sm[tid] += add;
        __syncthreads();
    }
    if (gid < N) {
        rowptr[gid] = sm[tid] - v;               // exclusive within chunk
        dinv[gid] = rsqrtf(1.0f + (float)v);     // +1 for self loop
    }
    if (tid == 255) partial[blockIdx.x] = sm[255];
}

// finish: every block redundantly scans the <=256 chunk partials in LDS (cheap)
// -> no separate scan_partials dispatch. (Verified correct in rounds 12/13.)

__global__ void scan_finish(int* __restrict__ rowptr, const int* __restrict__ partial,
                            int N, int E, int nchunks) {
    __shared__ int sm[256];
    int tid = threadIdx.x;
    sm[tid] = (tid < nchunks) ? partial[tid] : 0;
    __syncthreads();
#pragma unroll
    for (int off = 1; off < 256; off <<= 1) {
        int add = (tid >= off) ? sm[tid - off] : 0;
        __syncthreads();
        sm[tid] += add;
        __syncthreads();
    }
    int boff = (blockIdx.x == 0) ? 0 : sm[blockIdx.x - 1];
    __syncthreads();
    int gid = blockIdx.x * 256 + tid;
    if (gid < N) rowptr[gid] += boff;
    if (gid == 0) rowptr[N] = E;
}

// ---------------- atomic-free XCD-range-partitioned CSR scatter ----------------
// srcidx[rowptr[c] + rank] = src; ranks are a bijection onto [0, deg(c)).
// Range partitioning (block&7 -> XCD round-robin) keeps each srcidx line in one
// XCD's L2 so it writes back once. Kept SEPARATE from the gemm (round-10 lesson:
// fusing this latency-bound role into the heavy gemm capped occupancy, 8x regress).

__global__ void csr_scatter_part(const int* __restrict__ col, const uint* __restrict__ rr,
                                 const int* __restrict__ rowptr,
                                 ushort* __restrict__ srcidx, int E, int rangeSz) {
    int r = blockIdx.x & 7;
    int nsl = gridDim.x >> 3;
    int s = blockIdx.x >> 3;
    int lo = r * rangeSz;
    int hi = lo + rangeSz;
    int stride = nsl * blockDim.x;
    for (int e = s * blockDim.x + threadIdx.x; e < E; e += stride) {
        int c = col[e];
        if (c >= lo && c < hi) {
            uint v = rr[e];
            srcidx[rowptr[c] + (v >> 16)] = (ushort)(v & 0xffffu);
        }
    }
}

// ---------------- As1 = dinv * relu(x @ W1 + b1), bf16-packed, via bf16x3 MFMA --------
// Each wave: 16 rows x 64 cols, register double-buffered x tiles.
// W1 hi/lo fragments staged once per block in LDS (64 KB -> 2 blocks/CU).
// A/B K-mapping k=(lane>>4)*8+i used identically for both operands (K-perm invariant).
// C/D: col=lane&15, row=(lane>>4)*4+reg.

__global__ __launch_bounds__(256) void gemm1_mfma(const float* __restrict__ x,
                                                  const float* __restrict__ W1,
                                                  const float* __restrict__ b1,
                                                  const float* __restrict__ dinv,
                                                  uint* __restrict__ AsOut,
                                                  int MB, int totalWaves) {
    __shared__ uint4 wh_lds[2048];  // 32 KB: [ks][nt][lane] hi fragments
    __shared__ uint4 wl_lds[2048];  // 32 KB: lo fragments
    int tid = threadIdx.x;
    for (int e = tid; e < 2048; e += 256) {
        int ks = e >> 8;
        int rem = e & 255;
        int nt = rem >> 6;
        int ln = rem & 63;
        int k0 = ks * 32 + ((ln >> 4) << 3);
        int colw = nt * 16 + (ln & 15);
        ushort hi[8], lo[8];
#pragma unroll
        for (int i = 0; i < 8; ++i) {
            float v = W1[(k0 + i) * 64 + colw];
            split_bf16(v, hi[i], lo[i]);
        }
        wh_lds[e] = make_uint4(pack2(hi[0], hi[1]), pack2(hi[2], hi[3]),
                               pack2(hi[4], hi[5]), pack2(hi[6], hi[7]));
        wl_lds[e] = make_uint4(pack2(lo[0], lo[1]), pack2(lo[2], lo[3]),
                               pack2(lo[4], lo[5]), pack2(lo[6], lo[7]));
    }
    __syncthreads();

    int lane = tid & 63;
    int m = lane & 15;
    int kg = lane >> 4;
    int wid = blockIdx.x * 4 + (tid >> 6);
    const bf16x8* whf = reinterpret_cast<const bf16x8*>(wh_lds);
    const bf16x8* wlf = reinterpret_cast<const bf16x8*>(wl_lds);
    float bias[4];
#pragma unroll
    for (int nt = 0; nt < 4; ++nt) bias[nt] = b1[nt * 16 + m];

    auto load_tile = [&](float4* dst, int mbv) {
        const float4* xr = reinterpret_cast<const float4*>(x) +
                           (size_t)(mbv * 16 + m) * 64 + kg * 2;
#pragma unroll
        for (int ks = 0; ks < 8; ++ks) {
            dst[2 * ks]     = xr[ks * 8];
            dst[2 * ks + 1] = xr[ks * 8 + 1];
        }
    };

    int mb = wid;
    if (mb >= MB) return;
    float4 xv[16], xn[16];
    load_tile(xv, mb);

    while (true) {
        int mbn = mb + totalWaves;
        bool has_next = (mbn < MB);
        if (has_next) load_tile(xn, mbn);   // issue loads early; hide under MFMA

        f32x4 acc[4] = {{0.f,0.f,0.f,0.f},{0.f,0.f,0.f,0.f},
                        {0.f,0.f,0.f,0.f},{0.f,0.f,0.f,0.f}};
#pragma unroll
        for (int ks = 0; ks < 8; ++ks) {
            float4 a0 = xv[2 * ks];
            float4 a1 = xv[2 * ks + 1];
            float f[8] = {a0.x, a0.y, a0.z, a0.w, a1.x, a1.y, a1.z, a1.w};
            bf16x8 ah, al;
#pragma unroll
            for (int i = 0; i < 8; ++i) {
                ushort hu, lu;
                split_bf16(f[i], hu, lu);
                ah[i] = (short)hu;
                al[i] = (short)lu;
            }
#pragma unroll
            for (int nt = 0; nt < 4; ++nt) {
                bf16x8 wh = whf[(ks * 4 + nt) * 64 + lane];
                bf16x8 wl = wlf[(ks * 4 + nt) * 64 + lane];
                acc[nt] = __builtin_amdgcn_mfma_f32_16x16x32_bf16(ah, wh, acc[nt], 0, 0, 0);
                acc[nt] = __builtin_amdgcn_mfma_f32_16x16x32_bf16(al, wh, acc[nt], 0, 0, 0);
                acc[nt] = __builtin_amdgcn_mfma_f32_16x16x32_bf16(ah, wl, acc[nt], 0, 0, 0);
            }
        }

        int r0 = mb * 16 + kg * 4;
        float dr[4];
#pragma unroll
        for (int j = 0; j < 4; ++j) dr[j] = dinv[r0 + j];
#pragma unroll
        for (int nt = 0; nt < 4; ++nt) {
#pragma unroll
            for (int j = 0; j < 4; ++j) {
                float v = fmaxf(acc[nt][j] + bias[nt], 0.0f) * dr[j];
                float p = __shfl_xor(v, 1, 64);  // partner column (m^1)
                if ((m & 1) == 0) {
                    uint u = pack2(bf16_rne(v), bf16_rne(p));
                    AsOut[(size_t)(r0 + j) * 32 + ((nt * 16 + m) >> 1)] = u;
                }
            }
        }

        if (!has_next) break;
#pragma unroll
        for (int u = 0; u < 16; ++u) xv[u] = xn[u];
        mb = mbn;
    }
}

// ---------------- fused FAGCN layer, 8 nodes per wave ----------------
// 8 lanes per node, each lane owns 8 features (uint4 of bf16 pairs, 16 B/lane).
// One gather instruction fetches 8 edge-rows x 128 B = 1 KB useful; 4 gathers
// in flight per wave (two accumulator banks). Degree-sort refuted in round 14
// (layers are memory-system bound, not divergence bound) - natural node order.
// LAST variant fuses out = h @ W2 + b2 via LDS (2 output cols per lane).

template <bool LAST>
__global__ __launch_bounds__(256) void fagcn_layer(
    const uint4* __restrict__ As4, uint4* __restrict__ Out4,
    const float* __restrict__ dinv, const int* __restrict__ rowptr,
    const ushort* __restrict__ src, const float* __restrict__ att_l,
    const float* __restrict__ W2, const float* __restrict__ b2,
    float* __restrict__ out, int N) {
    __shared__ float W2s[64 * 16];   // 4 KB
    __shared__ float hL[32 * 68];    // 32 nodes x 64 (+4 pad)
    int tid = threadIdx.x;
    if (LAST) {
        for (int e = tid; e < 64 * 16; e += 256) W2s[e] = W2[e];
        __syncthreads();
    }
    int sub = tid & 7;               // feature octet index
    int lnode = tid >> 3;            // node within block (0..31)
    int i = blockIdx.x * 32 + lnode;
    if (i >= N) i = N - 1;           // duplicate last node (identical writes, benign)

    int start = rowptr[i];
    int end = rowptr[i + 1];
    const uint4* Ab = As4 + sub;
    uint4 su = Ab[(size_t)i * 8];
    float s0 = blo(su.x), s1 = bhi(su.x), s2 = blo(su.y), s3 = bhi(su.y);
    float s4 = blo(su.z), s5 = bhi(su.z), s6 = blo(su.w), s7 = bhi(su.w);

    float aA0=0.f,aA1=0.f,aA2=0.f,aA3=0.f,aA4=0.f,aA5=0.f,aA6=0.f,aA7=0.f;
    float aB0=0.f,aB1=0.f,aB2=0.f,aB3=0.f,aB4=0.f,aB5=0.f,aB6=0.f,aB7=0.f;
    int j = start;
    for (; j + 3 < end; j += 4) {
        int e0 = src[j];
        int e1 = src[j + 1];
        int e2 = src[j + 2];
        int e3 = src[j + 3];
        uint4 u0 = Ab[(size_t)e0 * 8];
        uint4 u1 = Ab[(size_t)e1 * 8];
        uint4 u2 = Ab[(size_t)e2 * 8];
        uint4 u3 = Ab[(size_t)e3 * 8];
        aA0 += blo(u0.x); aA1 += bhi(u0.x); aA2 += blo(u0.y); aA3 += bhi(u0.y);
        aA4 += blo(u0.z); aA5 += bhi(u0.z); aA6 += blo(u0.w); aA7 += bhi(u0.w);
        aB0 += blo(u1.x); aB1 += bhi(u1.x); aB2 += blo(u1.y); aB3 += bhi(u1.y);
        aB4 += blo(u1.z); aB5 += bhi(u1.z); aB6 += blo(u1.w); aB7 += bhi(u1.w);
        aA0 += blo(u2.x); aA1 += bhi(u2.x); aA2 += blo(u2.y); aA3 += bhi(u2.y);
        aA4 += blo(u2.z); aA5 += bhi(u2.z); aA6 += blo(u2.w); aA7 += bhi(u2.w);
        aB0 += blo(u3.x); aB1 += bhi(u3.x); aB2 += blo(u3.y); aB3 += bhi(u3.y);
        aB4 += blo(u3.z); aB5 += bhi(u3.z); aB6 += blo(u3.w); aB7 += bhi(u3.w);
    }
    for (; j < end; ++j) {
        int s = src[j];
        uint4 u = Ab[(size_t)s * 8];
        aA0 += blo(u.x); aA1 += bhi(u.x); aA2 += blo(u.y); aA3 += bhi(u.y);
        aA4 += blo(u.z); aA5 += bhi(u.z); aA6 += blo(u.w); aA7 += bhi(u.w);
    }
    float c0 = aA0 + aB0, c1 = aA1 + aB1, c2 = aA2 + aB2, c3 = aA3 + aB3;
    float c4 = aA4 + aB4, c5 = aA5 + aB5, c6 = aA6 + aB6, c7 = aA7 + aB7;

    float d = dinv[i];
    // gate = sigmoid(dot(h_row, att)) with h = As/d
    float4 at0 = reinterpret_cast<const float4*>(att_l)[2 * sub];
    float4 at1 = reinterpret_cast<const float4*>(att_l)[2 * sub + 1];
    float prod = s0 * at0.x + s1 * at0.y + s2 * at0.z + s3 * at0.w +
                 s4 * at1.x + s5 * at1.y + s6 * at1.z + s7 * at1.w;
#pragma unroll
    for (int off = 4; off > 0; off >>= 1)
        prod += __shfl_xor(prod, off, 64);   // fold within 8-lane group
    float gate = 1.0f / (1.0f + expf(-prod / d));
    float factor = gate * (1.0f + EPS) - EPS;
    float df = d * factor;
    float h0 = df * (c0 + s0), h1 = df * (c1 + s1);
    float h2 = df * (c2 + s2), h3 = df * (c3 + s3);
    float h4 = df * (c4 + s4), h5 = df * (c5 + s5);
    float h6 = df * (c6 + s6), h7 = df * (c7 + s7);

    if (!LAST) {
        Out4[(size_t)i * 8 + sub] =
            make_uint4(pack2(bf16_rne(d * h0), bf16_rne(d * h1)),
                       pack2(bf16_rne(d * h2), bf16_rne(d * h3)),
                       pack2(bf16_rne(d * h4), bf16_rne(d * h5)),
                       pack2(bf16_rne(d * h6), bf16_rne(d * h7)));
    } else {
        // fused gemm2: h -> LDS, then each lane computes 2 output columns
        float4* hrow4 = reinterpret_cast<float4*>(&hL[lnode * 68]);
        hrow4[2 * sub]     = make_float4(h0, h1, h2, h3);
        hrow4[2 * sub + 1] = make_float4(h4, h5, h6, h7);
        __syncthreads();
        const float4* h4p = reinterpret_cast<const float4*>(&hL[lnode * 68]);
        float accA = b2[sub];
        float accB = b2[sub + 8];
#pragma unroll
        for (int k4 = 0; k4 < 16; ++k4) {
            float4 hv = h4p[k4];
            int k = 4 * k4;
            accA = fmaf(hv.x, W2s[(k + 0) * 16 + sub], accA);
            accB = fmaf(hv.x, W2s[(k + 0) * 16 + sub + 8], accB);
            accA = fmaf(hv.y, W2s[(k + 1) * 16 + sub], accA);
            accB = fmaf(hv.y, W2s[(k + 1) * 16 + sub + 8], accB);
            accA = fmaf(hv.z, W2s[(k + 2) * 16 + sub], accA);
            accB = fmaf(hv.z, W2s[(k + 2) * 16 + sub + 8], accB);
            accA = fmaf(hv.w, W2s[(k + 3) * 16 + sub], accA);
            accB = fmaf(hv.w, W2s[(k + 3) * 16 + sub + 8], accB);
        }
        out[(size_t)i * 16 + sub] = accA;
        out[(size_t)i * 16 + sub + 8] = accB;
    }
}

extern "C" void kernel_launch(void* const* d_in, const int* in_sizes, int n_in,
                              void* d_out, int out_size, void* d_ws, size_t ws_size,
                              hipStream_t stream) {
    const float* x   = (const float*)d_in[0];   // [N, 256]
    const int*   ei  = (const int*)d_in[1];     // [2, E] flat (int32 per harness)
    const float* W1  = (const float*)d_in[2];   // [256, 64]
    const float* b1  = (const float*)d_in[3];   // [64]
    const float* att = (const float*)d_in[4];   // [L, 1, 64]
    const float* W2  = (const float*)d_in[5];   // [64, 16]
    const float* b2  = (const float*)d_in[6];   // [16]
    float* out = (float*)d_out;                 // [N, 16]

    const int N = in_sizes[0] / N_FEAT_IN;      // 50000 (< 65536: ushort ids/ranks)
    const int E = in_sizes[1] / 2;              // 800000
    const int L = in_sizes[4] / N_HID;          // 2 layers

    const int* row = ei;       // edge_index[0] (source)
    const int* col = ei + E;   // edge_index[1] (target)

    // workspace layout (256B-aligned regions)
    char* wp = (char*)d_ws;
    auto alloc = [&](size_t bytes) -> char* {
        char* p = wp;
        wp += (bytes + 255) & ~(size_t)255;
        return p;
    };
    float*  dinv    = (float*)alloc((size_t)N * 4);
    int*    cnt     = (int*)alloc((size_t)N * 4);
    int*    rowptr  = (int*)alloc((size_t)(N + 1) * 4);
    uint*   rr      = (uint*)alloc((size_t)E * 4);        // (rank<<16)|row per edge
    int*    partial = (int*)alloc(256 * 4);
    ushort* srcidx  = (ushort*)alloc((size_t)E * 2);
    uint*   AsA     = (uint*)alloc((size_t)N * 32 * 4);   // bf16-pair features
    uint*   AsB     = (uint*)alloc((size_t)N * 32 * 4);

    const int TB = 256;
    const int nchunks = (N + TB - 1) / TB;      // 196 <= 256
    const int rangeSz = (N + 7) / 8;            // XCD partition width
    const int PART_GRID = 1024;                 // 128 slices x 8 ranges

    // 1) degree+rank in ONE atomic pass -> dinv, rowptr; atomic-free CSR scatter
    zero_int<<<(N + TB - 1) / TB, TB, 0, stream>>>(cnt, N);
    hist_rank<<<(E + TB - 1) / TB, TB, 0, stream>>>(col, row, cnt, rr, E);
    scan_chunks<<<nchunks, TB, 0, stream>>>(cnt, rowptr, partial, dinv, N);
    scan_finish<<<nchunks, TB, 0, stream>>>(rowptr, partial, N, E, nchunks);
    csr_scatter_part<<<PART_GRID, TB, 0, stream>>>(col, rr, rowptr, srcidx, E, rangeSz);

    // 2) As1 = dinv * relu(x @ W1 + b1) -> AsA (bf16 pairs)
    {
        const int blocks = 512;                 // 64 KB LDS -> 2 blocks/CU
        const int MB = N / 16;                  // 3125 row-tiles
        gemm1_mfma<<<blocks, TB, 0, stream>>>(x, W1, b1, dinv, AsA, MB, blocks * 4);
    }

    // 3) FAGCN layers; LAST fuses the final h @ W2 + b2
    {
        int grid = (N + 31) / 32;               // 32 nodes per 256-thread block
        uint4* A = (uint4*)AsA;
        uint4* B = (uint4*)AsB;
        for (int l = 0; l < L; ++l) {
            const float* att_l = att + (size_t)l * N_HID;
            if (l == L - 1) {
                fagcn_layer<true><<<grid, TB, 0, stream>>>(
                    A, B, dinv, rowptr, srcidx, att_l, W2, b2, out, N);
            } else {
                fagcn_layer<false><<<grid, TB, 0, stream>>>(
                    A, B, dinv, rowptr, srcidx, att_l, W2, b2, out, N);
                uint4* tmp = A; A = B; B = tmp;
            }
        }
    }
}

// Round 16
// 122.815 us; speedup vs baseline: 1.1096x; 1.0353x over previous
//
#include <hip/hip_runtime.h>
#include <math.h>

#define N_FEAT_IN 256
#define N_HID 64
#define N_OUT 16
#define EPS 0.1f

typedef short bf16x8 __attribute__((ext_vector_type(8)));
typedef float f32x4 __attribute__((ext_vector_type(4)));

__device__ inline uint pack2(ushort a, ushort b) { return (uint)a | ((uint)b << 16); }

// fp32 -> bf16 round-to-nearest-even (inputs finite; no NaN handling needed)
__device__ inline ushort bf16_rne(float x) {
    uint b = __float_as_uint(x);
    b += 0x7fff + ((b >> 16) & 1);
    return (ushort)(b >> 16);
}

// unpack the two bf16 halves of a uint
__device__ inline float blo(uint u) { return __uint_as_float(u << 16); }
__device__ inline float bhi(uint u) { return __uint_as_float(u & 0xffff0000u); }

// truncation-based fp32 -> bf16 hi/lo split: x ~= hi + lo, |err| <= 2^-18 |x|
__device__ inline void split_bf16(float x, ushort& hi, ushort& lo) {
    uint b = __float_as_uint(x);
    hi = (ushort)(b >> 16);
    float xl = x - __uint_as_float(b & 0xffff0000u);
    lo = (ushort)(__float_as_uint(xl) >> 16);
}

// ---------------- zero (runtime fillBuffer is ~40us inside a graph) ----------------

__global__ void zero_int(int* __restrict__ p, int n) {
    int i = blockIdx.x * blockDim.x + threadIdx.x;
    if (i < n) p[i] = 0;
}

// ---------------- degree histogram, fused rank+row pack ----------------
// One atomic pass total: the atomic's return value IS the edge's rank among its
// target's edges. rr[e] = (rank<<16) | row[e] (both < 65536).

__global__ void hist_rank(const int* __restrict__ col, const int* __restrict__ row,
                          int* __restrict__ cnt, uint* __restrict__ rr, int E) {
    int e = blockIdx.x * blockDim.x + threadIdx.x;
    if (e < E) {
        int r = atomicAdd(&cnt[col[e]], 1);
        rr[e] = ((uint)r << 16) | (uint)row[e];
    }
}

// ---------------- 2-level exclusive scan (N <= 256*256), dinv fused ----------------

__global__ void scan_chunks(const int* __restrict__ cnt, int* __restrict__ rowptr,
                            int* __restrict__ partial, float* __restrict__ dinv, int N) {
    __shared__ int sm[256];
    int tid = threadIdx.x;
    int gid = blockIdx.x * 256 + tid;
    int v = (gid < N) ? cnt[gid] : 0;
    sm[tid] = v;
    __syncthreads();
#pragma unroll
    for (int off = 1; off < 256; off <<= 1) {
        int add = (tid >= off) ? sm[tid - off] : 0;
        __syncthreads();
        sm[tid] += add;
        __syncthreads();
    }
    if (gid < N) {
        rowptr[gid] = sm[tid] - v;               // exclusive within chunk
        dinv[gid] = rsqrtf(1.0f + (float)v);     // +1 for self loop
    }
    if (tid == 255) partial[blockIdx.x] = sm[255];
}

// finish: every block redundantly scans the <=256 chunk partials in LDS (cheap)

__global__ void scan_finish(int* __restrict__ rowptr, const int* __restrict__ partial,
                            int N, int E, int nchunks) {
    __shared__ int sm[256];
    int tid = threadIdx.x;
    sm[tid] = (tid < nchunks) ? partial[tid] : 0;
    __syncthreads();
#pragma unroll
    for (int off = 1; off < 256; off <<= 1) {
        int add = (tid >= off) ? sm[tid - off] : 0;
        __syncthreads();
        sm[tid] += add;
        __syncthreads();
    }
    int boff = (blockIdx.x == 0) ? 0 : sm[blockIdx.x - 1];
    __syncthreads();
    int gid = blockIdx.x * 256 + tid;
    if (gid < N) rowptr[gid] += boff;
    if (gid == 0) rowptr[N] = E;
}

// ---------------- atomic-free XCD-range-partitioned CSR scatter ----------------

__global__ void csr_scatter_part(const int* __restrict__ col, const uint* __restrict__ rr,
                                 const int* __restrict__ rowptr,
                                 ushort* __restrict__ srcidx, int E, int rangeSz) {
    int r = blockIdx.x & 7;
    int nsl = gridDim.x >> 3;
    int s = blockIdx.x >> 3;
    int lo = r * rangeSz;
    int hi = lo + rangeSz;
    int stride = nsl * blockDim.x;
    for (int e = s * blockDim.x + threadIdx.x; e < E; e += stride) {
        int c = col[e];
        if (c >= lo && c < hi) {
            uint v = rr[e];
            srcidx[rowptr[c] + (v >> 16)] = (ushort)(v & 0xffffu);
        }
    }
}

// ---------------- As1 = dinv * relu(x @ W1 + b1), bf16x3 MFMA, LDS-streamed x --------
// The MFMA A-fragment wants lane g*16+r to hold row r -> a register-direct x load
// is a 16B-granular scatter (measured 757 GB/s in R7). Fix: cooperatively stream
// each 16x256 x-tile into LDS with coalesced 16B/lane loads, then ds_read the
// fragments. float4-index XOR swizzle (c4 ^= r&7) keeps fragment reads bank-even
// with zero padding -> LDS = 64KB (W hi/lo) + 16KB (x) = 80KB -> 2 blocks/CU.
// Wave w owns output-column tile nt=w. K-perm-invariant mapping k=(lane>>4)*8+i
// used identically for A and B. C/D: col=lane&15, row=(lane>>4)*4+reg.

__global__ __launch_bounds__(256) void gemm1_mfma(const float* __restrict__ x,
                                                  const float* __restrict__ W1,
                                                  const float* __restrict__ b1,
                                                  const float* __restrict__ dinv,
                                                  uint* __restrict__ AsOut,
                                                  int MB) {
    __shared__ uint4 wh_lds[2048];   // 32 KB: [ks][nt][lane] hi fragments
    __shared__ uint4 wl_lds[2048];   // 32 KB: lo fragments
    __shared__ float4 xt4[1024];     // 16 KB: x tile, [r][c4 ^ (r&7)]
    int tid = threadIdx.x;
    for (int e = tid; e < 2048; e += 256) {
        int ks = e >> 8;
        int rem = e & 255;
        int nt = rem >> 6;
        int ln = rem & 63;
        int k0 = ks * 32 + ((ln >> 4) << 3);
        int colw = nt * 16 + (ln & 15);
        ushort hi[8], lo[8];
#pragma unroll
        for (int i = 0; i < 8; ++i) {
            float v = W1[(k0 + i) * 64 + colw];
            split_bf16(v, hi[i], lo[i]);
        }
        wh_lds[e] = make_uint4(pack2(hi[0], hi[1]), pack2(hi[2], hi[3]),
                               pack2(hi[4], hi[5]), pack2(hi[6], hi[7]));
        wl_lds[e] = make_uint4(pack2(lo[0], lo[1]), pack2(lo[2], lo[3]),
                               pack2(lo[4], lo[5]), pack2(lo[6], lo[7]));
    }
    // first loop iteration's __syncthreads() covers W staging

    int lane = tid & 63;
    int m = lane & 15;       // A row within tile / D col within nt-tile
    int g = lane >> 4;       // k-group
    int w = tid >> 6;        // wave id = output col-tile nt
    const bf16x8* whf = reinterpret_cast<const bf16x8*>(wh_lds);
    const bf16x8* wlf = reinterpret_cast<const bf16x8*>(wl_lds);
    float bias = b1[w * 16 + m];
    int swz = m & 7;

    for (int mb = blockIdx.x; mb < MB; mb += gridDim.x) {
        __syncthreads();     // xt4 free (prev tile's readers done; 1st iter: W staged)
        const float4* xg = reinterpret_cast<const float4*>(x) + (size_t)mb * 1024;
#pragma unroll
        for (int t = 0; t < 4; ++t) {
            int F = t * 256 + tid;          // float4 index within tile
            int r = F >> 6, c4 = F & 63;
            xt4[r * 64 + (c4 ^ (r & 7))] = xg[F];   // coalesced read, swizzled store
        }
        __syncthreads();

        f32x4 acc = {0.f, 0.f, 0.f, 0.f};
#pragma unroll
        for (int ks = 0; ks < 8; ++ks) {
            int c4 = ks * 8 + g * 2;
            float4 a0 = xt4[m * 64 + ((c4) ^ swz)];
            float4 a1 = xt4[m * 64 + ((c4 + 1) ^ swz)];
            float f[8] = {a0.x, a0.y, a0.z, a0.w, a1.x, a1.y, a1.z, a1.w};
            bf16x8 ah, al;
#pragma unroll
            for (int i = 0; i < 8; ++i) {
                ushort hu, lu;
                split_bf16(f[i], hu, lu);
                ah[i] = (short)hu;
                al[i] = (short)lu;
            }
            bf16x8 wh = whf[(ks * 4 + w) * 64 + lane];
            bf16x8 wl = wlf[(ks * 4 + w) * 64 + lane];
            acc = __builtin_amdgcn_mfma_f32_16x16x32_bf16(ah, wh, acc, 0, 0, 0);
            acc = __builtin_amdgcn_mfma_f32_16x16x32_bf16(al, wh, acc, 0, 0, 0);
            acc = __builtin_amdgcn_mfma_f32_16x16x32_bf16(ah, wl, acc, 0, 0, 0);
        }

        int r0 = mb * 16 + g * 4;
#pragma unroll
        for (int j = 0; j < 4; ++j) {
            float v = fmaxf(acc[j] + bias, 0.0f) * dinv[r0 + j];
            float p = __shfl_xor(v, 1, 64);  // partner column (m^1)
            if ((m & 1) == 0) {
                uint u = pack2(bf16_rne(v), bf16_rne(p));
                AsOut[(size_t)(r0 + j) * 32 + ((w * 16 + m) >> 1)] = u;
            }
        }
    }
}

// ---------------- fused FAGCN layer, 8 nodes per wave ----------------
// 8 lanes per node, each lane owns 8 features (uint4 of bf16 pairs, 16 B/lane).
// LAST variant fuses out = h @ W2 + b2 via LDS (2 output cols per lane).

template <bool LAST>
__global__ __launch_bounds__(256) void fagcn_layer(
    const uint4* __restrict__ As4, uint4* __restrict__ Out4,
    const float* __restrict__ dinv, const int* __restrict__ rowptr,
    const ushort* __restrict__ src, const float* __restrict__ att_l,
    const float* __restrict__ W2, const float* __restrict__ b2,
    float* __restrict__ out, int N) {
    __shared__ float W2s[64 * 16];   // 4 KB
    __shared__ float hL[32 * 68];    // 32 nodes x 64 (+4 pad)
    int tid = threadIdx.x;
    if (LAST) {
        for (int e = tid; e < 64 * 16; e += 256) W2s[e] = W2[e];
        __syncthreads();
    }
    int sub = tid & 7;               // feature octet index
    int lnode = tid >> 3;            // node within block (0..31)
    int i = blockIdx.x * 32 + lnode;
    if (i >= N) i = N - 1;           // duplicate last node (identical writes, benign)

    int start = rowptr[i];
    int end = rowptr[i + 1];
    const uint4* Ab = As4 + sub;
    uint4 su = Ab[(size_t)i * 8];
    float s0 = blo(su.x), s1 = bhi(su.x), s2 = blo(su.y), s3 = bhi(su.y);
    float s4 = blo(su.z), s5 = bhi(su.z), s6 = blo(su.w), s7 = bhi(su.w);

    float aA0=0.f,aA1=0.f,aA2=0.f,aA3=0.f,aA4=0.f,aA5=0.f,aA6=0.f,aA7=0.f;
    float aB0=0.f,aB1=0.f,aB2=0.f,aB3=0.f,aB4=0.f,aB5=0.f,aB6=0.f,aB7=0.f;
    int j = start;
    for (; j + 3 < end; j += 4) {
        int e0 = src[j];
        int e1 = src[j + 1];
        int e2 = src[j + 2];
        int e3 = src[j + 3];
        uint4 u0 = Ab[(size_t)e0 * 8];
        uint4 u1 = Ab[(size_t)e1 * 8];
        uint4 u2 = Ab[(size_t)e2 * 8];
        uint4 u3 = Ab[(size_t)e3 * 8];
        aA0 += blo(u0.x); aA1 += bhi(u0.x); aA2 += blo(u0.y); aA3 += bhi(u0.y);
        aA4 += blo(u0.z); aA5 += bhi(u0.z); aA6 += blo(u0.w); aA7 += bhi(u0.w);
        aB0 += blo(u1.x); aB1 += bhi(u1.x); aB2 += blo(u1.y); aB3 += bhi(u1.y);
        aB4 += blo(u1.z); aB5 += bhi(u1.z); aB6 += blo(u1.w); aB7 += bhi(u1.w);
        aA0 += blo(u2.x); aA1 += bhi(u2.x); aA2 += blo(u2.y); aA3 += bhi(u2.y);
        aA4 += blo(u2.z); aA5 += bhi(u2.z); aA6 += blo(u2.w); aA7 += bhi(u2.w);
        aB0 += blo(u3.x); aB1 += bhi(u3.x); aB2 += blo(u3.y); aB3 += bhi(u3.y);
        aB4 += blo(u3.z); aB5 += bhi(u3.z); aB6 += blo(u3.w); aB7 += bhi(u3.w);
    }
    for (; j < end; ++j) {
        int s = src[j];
        uint4 u = Ab[(size_t)s * 8];
        aA0 += blo(u.x); aA1 += bhi(u.x); aA2 += blo(u.y); aA3 += bhi(u.y);
        aA4 += blo(u.z); aA5 += bhi(u.z); aA6 += blo(u.w); aA7 += bhi(u.w);
    }
    float c0 = aA0 + aB0, c1 = aA1 + aB1, c2 = aA2 + aB2, c3 = aA3 + aB3;
    float c4 = aA4 + aB4, c5 = aA5 + aB5, c6 = aA6 + aB6, c7 = aA7 + aB7;

    float d = dinv[i];
    // gate = sigmoid(dot(h_row, att)) with h = As/d
    float4 at0 = reinterpret_cast<const float4*>(att_l)[2 * sub];
    float4 at1 = reinterpret_cast<const float4*>(att_l)[2 * sub + 1];
    float prod = s0 * at0.x + s1 * at0.y + s2 * at0.z + s3 * at0.w +
                 s4 * at1.x + s5 * at1.y + s6 * at1.z + s7 * at1.w;
#pragma unroll
    for (int off = 4; off > 0; off >>= 1)
        prod += __shfl_xor(prod, off, 64);   // fold within 8-lane group
    float gate = 1.0f / (1.0f + expf(-prod / d));
    float factor = gate * (1.0f + EPS) - EPS;
    float df = d * factor;
    float h0 = df * (c0 + s0), h1 = df * (c1 + s1);
    float h2 = df * (c2 + s2), h3 = df * (c3 + s3);
    float h4 = df * (c4 + s4), h5 = df * (c5 + s5);
    float h6 = df * (c6 + s6), h7 = df * (c7 + s7);

    if (!LAST) {
        Out4[(size_t)i * 8 + sub] =
            make_uint4(pack2(bf16_rne(d * h0), bf16_rne(d * h1)),
                       pack2(bf16_rne(d * h2), bf16_rne(d * h3)),
                       pack2(bf16_rne(d * h4), bf16_rne(d * h5)),
                       pack2(bf16_rne(d * h6), bf16_rne(d * h7)));
    } else {
        // fused gemm2: h -> LDS, then each lane computes 2 output columns
        float4* hrow4 = reinterpret_cast<float4*>(&hL[lnode * 68]);
        hrow4[2 * sub]     = make_float4(h0, h1, h2, h3);
        hrow4[2 * sub + 1] = make_float4(h4, h5, h6, h7);
        __syncthreads();
        const float4* h4p = reinterpret_cast<const float4*>(&hL[lnode * 68]);
        float accA = b2[sub];
        float accB = b2[sub + 8];
#pragma unroll
        for (int k4 = 0; k4 < 16; ++k4) {
            float4 hv = h4p[k4];
            int k = 4 * k4;
            accA = fmaf(hv.x, W2s[(k + 0) * 16 + sub], accA);
            accB = fmaf(hv.x, W2s[(k + 0) * 16 + sub + 8], accB);
            accA = fmaf(hv.y, W2s[(k + 1) * 16 + sub], accA);
            accB = fmaf(hv.y, W2s[(k + 1) * 16 + sub + 8], accB);
            accA = fmaf(hv.z, W2s[(k + 2) * 16 + sub], accA);
            accB = fmaf(hv.z, W2s[(k + 2) * 16 + sub + 8], accB);
            accA = fmaf(hv.w, W2s[(k + 3) * 16 + sub], accA);
            accB = fmaf(hv.w, W2s[(k + 3) * 16 + sub + 8], accB);
        }
        out[(size_t)i * 16 + sub] = accA;
        out[(size_t)i * 16 + sub + 8] = accB;
    }
}

extern "C" void kernel_launch(void* const* d_in, const int* in_sizes, int n_in,
                              void* d_out, int out_size, void* d_ws, size_t ws_size,
                              hipStream_t stream) {
    const float* x   = (const float*)d_in[0];   // [N, 256]
    const int*   ei  = (const int*)d_in[1];     // [2, E] flat (int32 per harness)
    const float* W1  = (const float*)d_in[2];   // [256, 64]
    const float* b1  = (const float*)d_in[3];   // [64]
    const float* att = (const float*)d_in[4];   // [L, 1, 64]
    const float* W2  = (const float*)d_in[5];   // [64, 16]
    const float* b2  = (const float*)d_in[6];   // [16]
    float* out = (float*)d_out;                 // [N, 16]

    const int N = in_sizes[0] / N_FEAT_IN;      // 50000 (< 65536: ushort ids/ranks)
    const int E = in_sizes[1] / 2;              // 800000
    const int L = in_sizes[4] / N_HID;          // 2 layers

    const int* row = ei;       // edge_index[0] (source)
    const int* col = ei + E;   // edge_index[1] (target)

    // workspace layout (256B-aligned regions)
    char* wp = (char*)d_ws;
    auto alloc = [&](size_t bytes) -> char* {
        char* p = wp;
        wp += (bytes + 255) & ~(size_t)255;
        return p;
    };
    float*  dinv    = (float*)alloc((size_t)N * 4);
    int*    cnt     = (int*)alloc((size_t)N * 4);
    int*    rowptr  = (int*)alloc((size_t)(N + 1) * 4);
    uint*   rr      = (uint*)alloc((size_t)E * 4);        // (rank<<16)|row per edge
    int*    partial = (int*)alloc(256 * 4);
    ushort* srcidx  = (ushort*)alloc((size_t)E * 2);
    uint*   AsA     = (uint*)alloc((size_t)N * 32 * 4);   // bf16-pair features
    uint*   AsB     = (uint*)alloc((size_t)N * 32 * 4);

    const int TB = 256;
    const int nchunks = (N + TB - 1) / TB;      // 196 <= 256
    const int rangeSz = (N + 7) / 8;            // XCD partition width
    const int PART_GRID = 1024;                 // 128 slices x 8 ranges

    // 1) degree+rank in ONE atomic pass -> dinv, rowptr; atomic-free CSR scatter
    zero_int<<<(N + TB - 1) / TB, TB, 0, stream>>>(cnt, N);
    hist_rank<<<(E + TB - 1) / TB, TB, 0, stream>>>(col, row, cnt, rr, E);
    scan_chunks<<<nchunks, TB, 0, stream>>>(cnt, rowptr, partial, dinv, N);
    scan_finish<<<nchunks, TB, 0, stream>>>(rowptr, partial, N, E, nchunks);
    csr_scatter_part<<<PART_GRID, TB, 0, stream>>>(col, rr, rowptr, srcidx, E, rangeSz);

    // 2) As1 = dinv * relu(x @ W1 + b1) -> AsA (bf16 pairs), LDS-streamed x
    {
        const int blocks = 512;                 // 80 KB LDS -> 2 blocks/CU
        const int MB = N / 16;                  // 3125 row-tiles
        gemm1_mfma<<<blocks, TB, 0, stream>>>(x, W1, b1, dinv, AsA, MB);
    }

    // 3) FAGCN layers; LAST fuses the final h @ W2 + b2
    {
        int grid = (N + 31) / 32;               // 32 nodes per 256-thread block
        uint4* A = (uint4*)AsA;
        uint4* B = (uint4*)AsB;
        for (int l = 0; l < L; ++l) {
            const float* att_l = att + (size_t)l * N_HID;
            if (l == L - 1) {
                fagcn_layer<true><<<grid, TB, 0, stream>>>(
                    A, B, dinv, rowptr, srcidx, att_l, W2, b2, out, N);
            } else {
                fagcn_layer<false><<<grid, TB, 0, stream>>>(
                    A, B, dinv, rowptr, srcidx, att_l, W2, b2, out, N);
                uint4* tmp = A; A = B; B = tmp;
            }
        }
    }
}